// Round 8
// baseline (205.856 us; speedup 1.0000x reference)
//
#include <hip/hip_runtime.h>

typedef __attribute__((ext_vector_type(8))) short short8;
typedef __attribute__((ext_vector_type(4))) float floatx4;

#define IN_C 128
#define OUT_C 256
#define NB 32
#define HW 56
#define S_PER_N (HW * HW)          // 3136
#define M_TOTAL (NB * S_PER_N)     // 100352
#define PH 58                      // padded height
#define PW 66                      // padded width
#define XN_ELEMS (NB * PH * PW * IN_C)   // 15,679,488
#define WT_ELEMS (9 * OUT_C * IN_C)      // 294,912
#define XF_BLOCKS (PH * NB)              // 1856 transform-x blocks
#define WF_BLOCKS (WT_ELEMS / 256)       // 1152 weight blocks

__device__ __forceinline__ unsigned short f2bf(float f) {
    unsigned int u = __builtin_bit_cast(unsigned int, f);
    u = (u + 0x7FFFu + ((u >> 16) & 1u)) >> 16;   // RNE
    return (unsigned short)u;
}

// Direct global->LDS DMA, 16B per lane. LDS dest must be base + lane*16.
__device__ __forceinline__ void gld_lds16(const unsigned short* g, unsigned short* l) {
    __builtin_amdgcn_global_load_lds(
        (const __attribute__((address_space(1))) unsigned int*)g,
        (__attribute__((address_space(3))) unsigned int*)l, 16, 0, 0);
}

// Fused transform kernel, 1D grid = XF_BLOCKS + WF_BLOCKS.
//   bid >= XF_BLOCKS: w (256,128,3,3) fp32 -> wt in MFMA-FRAGMENT ORDER:
//     patch = khw*64 + h*32 + kk*16 + oc16   (576 patches x 512 elems)
//     elem  = patch*512 + lane*8 + e, where lane=(quad<<4)|l15:
//       oc = oc16*16 + l15,  ic = h*64 + kk*32 + quad*8 + e.
//     => conv's A-fragment load is wt + uniform + lane*16B: contiguous 1KB/wave.
__global__ void xform_all(const float* __restrict__ x, const float* __restrict__ w,
                          unsigned short* __restrict__ xn, unsigned short* __restrict__ wt) {
    const int bid = blockIdx.x;
    const int tid = threadIdx.x;         // 256 threads

    if (bid >= XF_BLOCKS) {              // ---- weight transform (fragment order) ----
        const int u     = (bid - XF_BLOCKS) * 256 + tid;
        const int patch = u >> 9;        // 0..575
        const int lane  = (u >> 3) & 63;
        const int e     = u & 7;
        const int khw   = patch / 64;
        const int rem   = patch & 63;
        const int h     = rem >> 5;
        const int kk    = (rem >> 4) & 1;
        const int oc16  = rem & 15;
        const int oc = oc16 * 16 + (lane & 15);
        const int ic = h * 64 + kk * 32 + (lane >> 4) * 8 + e;
        wt[u] = f2bf(w[(oc * IN_C + ic) * 9 + khw]);
        return;
    }

    const int ihp = bid % PH;            // 0..57
    const int n   = bid / PH;            // 0..31
    unsigned int* __restrict__ row32 =
        (unsigned int*)(xn + (size_t)(n * PH + ihp) * PW * IN_C);
    const int WORDS = PW * IN_C / 2;     // 4224 uint32 per padded row

    if (ihp == 0 || ihp == PH - 1) {     // top/bottom halo rows
        for (int i = tid; i < WORDS; i += 256) row32[i] = 0u;
        return;
    }
    // left/right halo words (pix 0 and 65): 128 words
    if (tid < 128) {
        int p = (tid >> 6) * (PW - 1);   // 0 or 65
        row32[p * 64 + (tid & 63)] = 0u;
    }
    const int ih = ihp - 1;
    const float* __restrict__ xrow = x + (size_t)n * IN_C * S_PER_N + (size_t)ih * HW;
#pragma unroll
    for (int t = 0; t < 4; ++t) {
        const int item = tid + t * 256;
        if (item >= 64 * 14) break;
        const int icw  = item & 63;
        const int pix4 = item >> 6;      // 0..13 -> iw 4*pix4..+3
        const float4 v0 = *(const float4*)(xrow + (size_t)(2 * icw)     * S_PER_N + pix4 * 4);
        const float4 v1 = *(const float4*)(xrow + (size_t)(2 * icw + 1) * S_PER_N + pix4 * 4);
        unsigned int* o = row32 + (pix4 * 4 + 1) * 64 + icw;
        o[0]   = (unsigned int)f2bf(v0.x) | ((unsigned int)f2bf(v1.x) << 16);
        o[64]  = (unsigned int)f2bf(v0.y) | ((unsigned int)f2bf(v1.y) << 16);
        o[128] = (unsigned int)f2bf(v0.z) | ((unsigned int)f2bf(v1.z) << 16);
        o[192] = (unsigned int)f2bf(v0.w) | ((unsigned int)f2bf(v1.w) << 16);
    }
}

// Implicit GEMM (R7 schedule; A direct-to-register, B LDS-staged):
//   block 128 oc x 128 s, 4 waves, wave 64x64 (4x4 of 16x16x32 bf16 MFMA), BK=64,
//   2-barrier per K-step, LDS 16 KB (B only) single-buffered.
// A (weights, 576 KB total, L2/L1-resident) is loaded straight to VGPRs from the
//   fragment-ordered wt: per (khw,h,kk) one uniform patch base + lane*16B ->
//   4 contiguous 1KB wave-loads. Halves LDS-port traffic (reads 16->8 b128,
//   DMA writes 8->4 per thread/K-step) and halves the staging drain.
// B keeps T21 both-sides XOR swizzle (slot u ^= row&7): 0 bank conflicts.
// T1 bijective XCD swizzle: grid 1568 = 8*196.
// Register budget: VGPR<=64 + acc 64 AGPR = 128 -> 4 waves/SIMD (proven lever).
__global__ void __launch_bounds__(256, 4)
conv_mfma(const unsigned short* __restrict__ xn,
          const unsigned short* __restrict__ wt,
          float* __restrict__ out) {
    const int tid  = threadIdx.x;
    const int lane = tid & 63;
    const int wv   = tid >> 6;        // 0..3
    const int l15  = lane & 15;
    const int quad = lane >> 4;       // 0..3
    const int fr7  = l15 & 7;

    const int bx0 = blockIdx.x;
    const int bx  = (bx0 & 7) * 196 + (bx0 >> 3);   // XCD-contiguous remap
    const int tile_oc = bx & 1;       // 2 oc tiles of 128
    const int tile_m  = bx >> 1;      // 784 spatial tiles of 128

    const int s_blk  = tile_m * 128;
    const int oc_blk = tile_oc * 128;

    __shared__ unsigned short B_lds[128 * 64];   // [s_local][ic64] 16 KB (swizzled)

    // ---- B staging: thread covers (row = q*32 + tid>>3, slot = tid&7) ----
    const int srow = tid >> 3;          // 0..31 ; (q*32+srow)&7 == srow&7
    const int sic  = ((tid & 7) ^ (srow & 7)) * 8;   // T21 source-side swizzle

    unsigned int boff[4];
#pragma unroll
    for (int q = 0; q < 4; ++q) {
        int sg = s_blk + q * 32 + srow;
        int n  = sg / S_PER_N;
        int r  = sg % S_PER_N;
        int oh = r / HW, ow = r % HW;
        boff[q] = (unsigned int)(((n * PH + oh) * PW + ow) * IN_C + sic);
    }

    // ---- fragment read offsets ----
    // B (LDS): elem(row,kk) = row*64 + ((quad^fr7)*8 ^ kk*32); row = (wv&1)*64 + j*16 + l15.
    const int bof0 = ((wv & 1) * 64 + l15) * 64 + (quad ^ fr7) * 8;
    // A (global, fragment-ordered): patch = khw*64 + h*32 + kk*16 + oc16,
    //   oc16 for this wave = tile_oc*8 + (wv>>1)*4 + i.  Load = wt + patch*512 + lane*8.
    const int pb_wave  = tile_oc * 8 + (wv >> 1) * 4;
    const unsigned lv8 = (unsigned)(lane * 8);       // per-lane voffset (elements)

    floatx4 acc[4][4];
#pragma unroll
    for (int i = 0; i < 4; ++i)
#pragma unroll
        for (int j = 0; j < 4; ++j) acc[i][j] = (floatx4){0.f, 0.f, 0.f, 0.f};

#pragma unroll
    for (int khw = 0; khw < 9; ++khw) {
        const int xo = ((khw / 3) * PW + (khw % 3)) * IN_C;  // activation k-offset
#pragma unroll
        for (int h = 0; h < 2; ++h) {
            const int ic0 = h * 64;
            __syncthreads();                      // previous tile consumed
#pragma unroll
            for (int q = 0; q < 4; ++q)
                gld_lds16(xn + (boff[q] + (unsigned)(xo + ic0)), B_lds + q * 2048 + tid * 8);
            __syncthreads();                      // B tile loaded (vmcnt drained)

#pragma unroll
            for (int kk = 0; kk < 2; ++kk) {
                // A fragments straight from global (L2-resident, contiguous 1KB/wave)
                const unsigned pbase =
                    (unsigned)((khw * 64 + h * 32 + kk * 16 + pb_wave) * 512) + lv8;
                short8 a[4], b[4];
#pragma unroll
                for (int i = 0; i < 4; ++i) a[i] = *(const short8*)(wt + pbase + i * 512);
                const int kb = bof0 ^ (kk * 32);
#pragma unroll
                for (int j = 0; j < 4; ++j) b[j] = *(const short8*)(B_lds + kb + j * 1024);
#pragma unroll
                for (int i = 0; i < 4; ++i)
#pragma unroll
                    for (int j = 0; j < 4; ++j)
                        acc[i][j] = __builtin_amdgcn_mfma_f32_16x16x32_bf16(
                            a[i], b[j], acc[i][j], 0, 0, 0);
            }
        }
    }

    // Epilogue: C/D layout col=lane&15 (s), row=quad*4+reg (oc). 32-bit addressing.
    const int s0  = s_blk + (wv & 1) * 64;
    const int oc0 = oc_blk + (wv >> 1) * 64;
#pragma unroll
    for (int j = 0; j < 4; ++j) {
        int s_glob = s0 + j * 16 + l15;
        int n = s_glob / S_PER_N;
        int s = s_glob % S_PER_N;
        unsigned int obase = (unsigned int)(n * OUT_C * S_PER_N + s);
#pragma unroll
        for (int i = 0; i < 4; ++i) {
            unsigned int ooff = obase + (unsigned int)((oc0 + i * 16 + quad * 4) * S_PER_N);
#pragma unroll
            for (int r = 0; r < 4; ++r)
                out[ooff + (unsigned int)(r * S_PER_N)] = acc[i][j][r];
        }
    }
}

extern "C" void kernel_launch(void* const* d_in, const int* in_sizes, int n_in,
                              void* d_out, int out_size, void* d_ws, size_t ws_size,
                              hipStream_t stream) {
    const float* x = (const float*)d_in[0];
    const float* w = (const float*)d_in[1];
    float* out = (float*)d_out;

    unsigned short* xn = (unsigned short*)d_ws;      // 31,358,976 B
    unsigned short* wt = xn + XN_ELEMS;              // 589,824 B

    xform_all<<<XF_BLOCKS + WF_BLOCKS, 256, 0, stream>>>(x, w, xn, wt);
    conv_mfma<<<(M_TOTAL / 128) * 2, 256, 0, stream>>>(xn, wt, out);
}

// Round 9
// 200.377 us; speedup vs baseline: 1.0273x; 1.0273x over previous
//
#include <hip/hip_runtime.h>

typedef __attribute__((ext_vector_type(8))) short short8;
typedef __attribute__((ext_vector_type(4))) float floatx4;

#define IN_C 128
#define OUT_C 256
#define NB 32
#define HW 56
#define S_PER_N (HW * HW)          // 3136
#define M_TOTAL (NB * S_PER_N)     // 100352
#define PH 58                      // padded height
#define PW 66                      // padded width
#define XN_ELEMS (NB * PH * PW * IN_C)   // 15,679,488
#define WT_ELEMS (9 * OUT_C * IN_C)      // 294,912
#define XF_BLOCKS (PH * NB)              // 1856 transform-x blocks
#define WF_BLOCKS (WT_ELEMS / 256)       // 1152 weight blocks

__device__ __forceinline__ unsigned short f2bf(float f) {
    unsigned int u = __builtin_bit_cast(unsigned int, f);
    u = (u + 0x7FFFu + ((u >> 16) & 1u)) >> 16;   // RNE
    return (unsigned short)u;
}

// Direct global->LDS DMA, 16B per lane. LDS dest must be base + lane*16.
__device__ __forceinline__ void gld_lds16(const unsigned short* g, unsigned short* l) {
    __builtin_amdgcn_global_load_lds(
        (const __attribute__((address_space(1))) unsigned int*)g,
        (__attribute__((address_space(3))) unsigned int*)l, 16, 0, 0);
}

// Fused transform kernel, 1D grid = XF_BLOCKS + WF_BLOCKS.
//   x-branch: uint2 packed stores (4 ch/lane/item) -> 33% fewer mem instrs
//   than the R3 version (stores halved, loads unchanged: each float4 read once).
//   w-branch: plain [khw][oc][ic] layout (matches R7 conv's LDS-staged A).
__global__ void xform_all(const float* __restrict__ x, const float* __restrict__ w,
                          unsigned short* __restrict__ xn, unsigned short* __restrict__ wt) {
    const int bid = blockIdx.x;
    const int tid = threadIdx.x;         // 256 threads

    if (bid >= XF_BLOCKS) {              // ---- weight transform ----
        const int idx = (bid - XF_BLOCKS) * 256 + tid;
        const int ic  = idx & 127;
        const int oc  = (idx >> 7) & 255;
        const int khw = idx >> 15;
        wt[idx] = f2bf(w[(oc * IN_C + ic) * 9 + khw]);
        return;
    }

    const int ihp = bid % PH;            // 0..57
    const int n   = bid / PH;            // 0..31
    unsigned int* __restrict__ row32 =
        (unsigned int*)(xn + (size_t)(n * PH + ihp) * PW * IN_C);
    const int WORDS = PW * IN_C / 2;     // 4224 uint32 per padded row

    if (ihp == 0 || ihp == PH - 1) {     // top/bottom halo rows
        for (int i = tid; i < WORDS; i += 256) row32[i] = 0u;
        return;
    }
    // left/right halo words (pix 0 and 65): 128 words
    if (tid < 128) {
        int p = (tid >> 6) * (PW - 1);   // 0 or 65
        row32[p * 64 + (tid & 63)] = 0u;
    }
    const int ih = ihp - 1;
    const float* __restrict__ xrow = x + (size_t)n * IN_C * S_PER_N + (size_t)ih * HW;
    unsigned long long* __restrict__ row64 = (unsigned long long*)row32;
    // items: (icw2 0..31) x (pix4 0..13) = 448; icw2 = 4-channel group, pix4 = 4 pixels
#pragma unroll
    for (int t = 0; t < 2; ++t) {
        const int item = tid + t * 256;
        if (item >= 32 * 14) break;
        const int icw2 = item & 31;      // channels 4*icw2 .. 4*icw2+3
        const int pix4 = item >> 5;      // 0..13 -> iw 4*pix4..+3
        const float* cbase = xrow + (size_t)(4 * icw2) * S_PER_N + pix4 * 4;
        const float4 v0 = *(const float4*)(cbase);
        const float4 v1 = *(const float4*)(cbase + S_PER_N);
        const float4 v2 = *(const float4*)(cbase + 2 * S_PER_N);
        const float4 v3 = *(const float4*)(cbase + 3 * S_PER_N);
        // output uint2 per pixel: lo = ch0|ch1<<16, hi = ch2|ch3<<16
        unsigned long long* o = row64 + (size_t)(pix4 * 4 + 1) * 32 + icw2;
#define PACK2(a, b, c, d) ((unsigned long long)((unsigned int)f2bf(a) | ((unsigned int)f2bf(b) << 16)) \
                         | ((unsigned long long)((unsigned int)f2bf(c) | ((unsigned int)f2bf(d) << 16)) << 32))
        o[0]  = PACK2(v0.x, v1.x, v2.x, v3.x);
        o[32] = PACK2(v0.y, v1.y, v2.y, v3.y);
        o[64] = PACK2(v0.z, v1.z, v2.z, v3.z);
        o[96] = PACK2(v0.w, v1.w, v2.w, v3.w);
#undef PACK2
    }
}

// Implicit GEMM (R7 session-best, byte-identical revert):
//   block 128 oc x 128 s, 4 waves, wave 64x64 (4x4 of 16x16x32 bf16 MFMA), BK=64,
//   2-barrier per K-step, LDS 32 KB single-buffered (A 16 KB + B 16 KB).
// Register diet: 32-bit offsets from uniform bases, fragment offsets collapsed
//   to 2 scalars (+i*1024 folded into ds_read immediates).
//   VGPR 64 + AGPR 64 = 128 -> 4 waves/SIMD = 4 blocks/CU (the proven lever).
// T21 both-sides XOR swizzle (slot u ^= row&7): 0 bank conflicts.
// T1 bijective XCD swizzle: grid 1568 = 8*196.
__global__ void __launch_bounds__(256, 4)
conv_mfma(const unsigned short* __restrict__ xn,
          const unsigned short* __restrict__ wt,
          float* __restrict__ out) {
    const int tid  = threadIdx.x;
    const int lane = tid & 63;
    const int wv   = tid >> 6;        // 0..3
    const int l15  = lane & 15;
    const int quad = lane >> 4;       // 0..3
    const int fr7  = l15 & 7;

    const int bx0 = blockIdx.x;
    const int bx  = (bx0 & 7) * 196 + (bx0 >> 3);   // XCD-contiguous remap
    const int tile_oc = bx & 1;       // 2 oc tiles of 128
    const int tile_m  = bx >> 1;      // 784 spatial tiles of 128

    const int s_blk  = tile_m * 128;
    const int oc_blk = tile_oc * 128;

    __shared__ unsigned short A_lds[128 * 64];   // [oc_local][ic64] 16 KB (swizzled)
    __shared__ unsigned short B_lds[128 * 64];   // [s_local][ic64]  16 KB (swizzled)

    // ---- staging: thread covers (row = q*32 + tid>>3, slot = tid&7), 32-bit offs ----
    const int srow = tid >> 3;          // 0..31 ; (q*32+srow)&7 == srow&7
    const int sic  = ((tid & 7) ^ (srow & 7)) * 8;   // T21 source-side swizzle

    unsigned int aoff[4], boff[4];
#pragma unroll
    for (int q = 0; q < 4; ++q) {
        int row = q * 32 + srow;
        aoff[q] = (unsigned int)((oc_blk + row) * IN_C + sic);
        int sg = s_blk + row;
        int n  = sg / S_PER_N;
        int r  = sg % S_PER_N;
        int oh = r / HW, ow = r % HW;
        boff[q] = (unsigned int)(((n * PH + oh) * PW + ow) * IN_C + sic);
    }

    // ---- fragment read offsets: base + i*1024 (folded into ds_read imm) ----
    // elem(row,kk) = row*64 + ((quad^fr7)*8 ^ kk*32); row = wrow0 + i*16.
    const int slot = (quad ^ fr7) * 8;
    const int aof0 = ((wv >> 1) * 64 + l15) * 64 + slot;
    const int bof0 = ((wv & 1)  * 64 + l15) * 64 + slot;

    floatx4 acc[4][4];
#pragma unroll
    for (int i = 0; i < 4; ++i)
#pragma unroll
        for (int j = 0; j < 4; ++j) acc[i][j] = (floatx4){0.f, 0.f, 0.f, 0.f};

#pragma unroll
    for (int khw = 0; khw < 9; ++khw) {
        const int xo = ((khw / 3) * PW + (khw % 3)) * IN_C;  // activation k-offset
        const int wo = khw * OUT_C * IN_C;                   // weight k-offset
#pragma unroll
        for (int h = 0; h < 2; ++h) {
            const int ic0 = h * 64;
            __syncthreads();                      // previous tile consumed
#pragma unroll
            for (int q = 0; q < 4; ++q) {
                gld_lds16(wt + (aoff[q] + (unsigned)(wo + ic0)), A_lds + q * 2048 + tid * 8);
                gld_lds16(xn + (boff[q] + (unsigned)(xo + ic0)), B_lds + q * 2048 + tid * 8);
            }
            __syncthreads();                      // tile loaded (vmcnt drained)

#pragma unroll
            for (int kk = 0; kk < 2; ++kk) {
                const int ka = aof0 ^ (kk * 32);  // XOR hoisted: (x+i*1024)^32 == (x^32)+i*1024
                const int kb = bof0 ^ (kk * 32);
                short8 a[4], b[4];
#pragma unroll
                for (int i = 0; i < 4; ++i) a[i] = *(const short8*)(A_lds + ka + i * 1024);
#pragma unroll
                for (int j = 0; j < 4; ++j) b[j] = *(const short8*)(B_lds + kb + j * 1024);
#pragma unroll
                for (int i = 0; i < 4; ++i)
#pragma unroll
                    for (int j = 0; j < 4; ++j)
                        acc[i][j] = __builtin_amdgcn_mfma_f32_16x16x32_bf16(
                            a[i], b[j], acc[i][j], 0, 0, 0);
            }
        }
    }

    // Epilogue: C/D layout col=lane&15 (s), row=quad*4+reg (oc). 32-bit addressing.
    const int s0  = s_blk + (wv & 1) * 64;
    const int oc0 = oc_blk + (wv >> 1) * 64;
#pragma unroll
    for (int j = 0; j < 4; ++j) {
        int s_glob = s0 + j * 16 + l15;
        int n = s_glob / S_PER_N;
        int s = s_glob % S_PER_N;
        unsigned int obase = (unsigned int)(n * OUT_C * S_PER_N + s);
#pragma unroll
        for (int i = 0; i < 4; ++i) {
            unsigned int ooff = obase + (unsigned int)((oc0 + i * 16 + quad * 4) * S_PER_N);
#pragma unroll
            for (int r = 0; r < 4; ++r)
                out[ooff + (unsigned int)(r * S_PER_N)] = acc[i][j][r];
        }
    }
}

extern "C" void kernel_launch(void* const* d_in, const int* in_sizes, int n_in,
                              void* d_out, int out_size, void* d_ws, size_t ws_size,
                              hipStream_t stream) {
    const float* x = (const float*)d_in[0];
    const float* w = (const float*)d_in[1];
    float* out = (float*)d_out;

    unsigned short* xn = (unsigned short*)d_ws;      // 31,358,976 B
    unsigned short* wt = xn + XN_ELEMS;              // 589,824 B

    xform_all<<<XF_BLOCKS + WF_BLOCKS, 256, 0, stream>>>(x, w, xn, wt);
    conv_mfma<<<(M_TOTAL / 128) * 2, 256, 0, stream>>>(xn, wt, out);
}